// Round 10
// baseline (230.234 us; speedup 1.0000x reference)
//
#include <hip/hip_runtime.h>
#include <cstdint>

// ---------------------------------------------------------------------------
// AttentionBlock: B=2, C=512, H=W=64 (S=4096), 8 heads x 64 dim.
// I/O dtype: fp32. Internal: bf16 MFMA, fp32 accum.
// R25 = R24 base (verified 217.3us total; attn 82.7) + ONE structural change:
// attn128 MFMA shape 16x16x32 -> 32x32x16.
//  - QKT: 2 j-tiles x 4 k-slices = 8 mfma (was 16); PV: 2 d-tiles x 4
//    j-slices = 8 (was 16); lacc: 4 (was 4). Matrix 180->160 cyc/tile,
//    issue slots 36->20.
//  - P redistribution SIMPLIFIES: per j-slice js, swap32(W[4s+0],W[4s+2])
//    and swap32(W[4s+1],W[4s+3]) directly produce the 4 B-frag words
//    (derived from the R16-verified permlane32_swap semantics:
//    a'=[a.lo32, c.lo32], c'=[a.hi32, c.hi32] per-quarter comment form).
//    permlane16 eliminated: 8 swaps/tile vs 16.
//  - 32x32 layouts: C/D col=lane&31=i, row=(r&3)+8(r>>2)+4*(lane>>5)
//    [m74/m101]; A/B row=lane&31, k=(lane>>5)*8+e. cvt_pk(s[2u],s[2u+1])
//    gives consecutive-j words for all u. LDS chunk reads
//    ((2*slice+hh)^(lane&7)) hit every chunk with exactly 8 lanes = the
//    wave-b128 minimum (0 excess conflicts), same as 16x16 pattern.
//  - Epilogue: reg quads r=4u..4u+3 are consecutive d -> same u16x4 stores;
//    l[i] = lacc32[0] on lanes<32 (all C rows identical for ones-A).
// Everything else identical to R24 (staging, quad-buffer, 2-tile barrier,
// combine kernel, gemm_qkv/gemm_out, ones-MFMA l-sum on matrix pipe).
// R24 post-mortem: l-sum on matrix pipe = -4us (predicted); at 86% combined
// pipe-busy only work-removal pays.
// 16x16 B^T-form (gemm kernels): C[m][n] += A[m][k]*B[n][k]; C/D
// col(n)=lane&15, row(m)=lq*4+reg; A/B frag: row=lane&15, k=lq*8+j.
// ---------------------------------------------------------------------------

typedef __bf16 bf16x8 __attribute__((ext_vector_type(8)));
typedef __bf16 bf16x4 __attribute__((ext_vector_type(4)));
typedef float f32x4 __attribute__((ext_vector_type(4)));
typedef float f32x16 __attribute__((ext_vector_type(16)));
typedef unsigned short u16x8 __attribute__((ext_vector_type(8)));
typedef unsigned short u16x4 __attribute__((ext_vector_type(4)));

#define AS1 __attribute__((address_space(1)))
#define AS3 __attribute__((address_space(3)))

__device__ __forceinline__ void async16(const void* g, void* l) {
  __builtin_amdgcn_global_load_lds((const AS1 void*)g, (AS3 void*)l, 16, 0, 0);
}

__device__ __forceinline__ uint16_t f2bf(float f) {
  union { float f; uint32_t u; } a;
  a.f = f;
  uint32_t r = a.u + 0x7fffu + ((a.u >> 16) & 1u);  // RNE
  return (uint16_t)(r >> 16);
}

__device__ __forceinline__ float bf2f(uint16_t u) {
  union { uint32_t u; float f; } a;
  a.u = (uint32_t)u << 16;
  return a.f;
}

// ---------------------------------------------------------------------------
__global__ __launch_bounds__(256) void cvt_w(
    const float* __restrict__ W0, const float* __restrict__ W1,
    const float* __restrict__ W2, const float* __restrict__ W3,
    uint16_t* __restrict__ O0, uint16_t* __restrict__ O1,
    uint16_t* __restrict__ O2, uint16_t* __restrict__ O3) {
  const float* W[4] = {W0, W1, W2, W3};
  uint16_t* O[4] = {O0, O1, O2, O3};
  const int w = blockIdx.y;
  const int i = (blockIdx.x * 256 + threadIdx.x) * 4;
  float4 v = *(const float4*)&W[w][i];
  u16x4 o = {f2bf(v.x), f2bf(v.y), f2bf(v.z), f2bf(v.w)};
  *(u16x4*)&O[w][i] = o;
}

// ---------------------------------------------------------------------------
// Transpose+convert [C=512][S=4096] fp32 -> [S][C] bf16, x and context.
// ---------------------------------------------------------------------------
__global__ __launch_bounds__(256) void transpose_cs(
    const float* __restrict__ x, const float* __restrict__ ctx,
    uint16_t* __restrict__ xT, uint16_t* __restrict__ cT) {
  const int zz = blockIdx.z;
  const float* src = (zz < 2 ? x : ctx) + (size_t)(zz & 1) * 512 * 4096;
  uint16_t* dst = (zz < 2 ? xT : cT) + (size_t)(zz & 1) * 4096 * 512;
  const int s0 = blockIdx.x * 64, c0 = blockIdx.y * 64;
  __shared__ uint16_t tile[64][80];
  const int t = threadIdx.x;
  for (int p = 0; p < 2; ++p) {
    int u = p * 256 + t;
    int r = u >> 3, cg = (u & 7) * 8;
    const float* sp = &src[(size_t)(c0 + r) * 4096 + s0 + cg];
    float4 v0 = *(const float4*)sp;
    float4 v1 = *(const float4*)(sp + 4);
    u16x8 o = {f2bf(v0.x), f2bf(v0.y), f2bf(v0.z), f2bf(v0.w),
               f2bf(v1.x), f2bf(v1.y), f2bf(v1.z), f2bf(v1.w)};
    *(u16x8*)&tile[r][cg] = o;
  }
  __syncthreads();
  for (int p = 0; p < 2; ++p) {
    int u = p * 256 + t;
    int sr = u >> 3, cg = (u & 7) * 8;
    u16x8 v;
    for (int j = 0; j < 8; ++j) v[j] = tile[cg + j][sr];
    *(u16x8*)&dst[(size_t)(s0 + sr) * 512 + c0 + cg] = v;
  }
}

// ---------------------------------------------------------------------------
// Fused QKV projection. blockIdx.z = sel*2 + batch, sel in {0:Q, 1:K, 2:V}.
// C[m][n] = (sum_k A[m][k]*B[n][k] + bias) * os, stored at C[col*ldC + row]
// (row = m is the contiguous dim -> u16x4 stores).
// Q/K: A=W (m=e), B=xT/cT (n=s), out Q[s][e] (ldC=512), bias by row.
// V:   A=cT (m=s), B=Wv (n=e), out Vt[e][s] (ldC=4096), bias by col.
// ---------------------------------------------------------------------------
struct QkvArgs {
  const uint16_t* A[3]; long long sA[3];
  const uint16_t* B[3]; long long sB[3];
  uint16_t* C[3];       long long sC[3];
  const float* bias[3];
  float os[3];
  long long ldC[3]; int lx[3]; int brow[3];
};

__global__ __launch_bounds__(256) void gemm_qkv(QkvArgs ga) {
  constexpr int K = 512;
  __shared__ uint16_t At[128 * 32];
  __shared__ uint16_t Bt[128 * 32];
  const int t = threadIdx.x, lane = t & 63, wave = t >> 6;
  const int lr = lane & 15, lq = lane >> 4;
  const int wm = (wave >> 1) * 64, wn = (wave & 1) * 64;
  const int sel = blockIdx.z >> 1, bat = blockIdx.z & 1;
  const int lx = ga.lx[sel], brow = ga.brow[sel];
  const long long ldC = ga.ldC[sel];
  const float os = ga.os[sel];
  const int n0 = (blockIdx.x & ((1 << lx) - 1)) * 128;
  const int m0 = (blockIdx.x >> lx) * 128;
  const uint16_t* A = ga.A[sel] + (size_t)bat * ga.sA[sel];
  const uint16_t* B = ga.B[sel] + (size_t)bat * ga.sB[sel];
  const float* bias = ga.bias[sel];
  f32x4 acc[4][4] = {};
  for (int k0 = 0; k0 < K; k0 += 32) {
    __syncthreads();
    for (int p = 0; p < 2; ++p) {
      int u = p * 256 + t;
      int r = u >> 2, c = (u & 3) * 8;
      async16(&A[(size_t)(m0 + r) * K + k0 + c], &At[p * 2048 + wave * 512]);
      async16(&B[(size_t)(n0 + r) * K + k0 + c], &Bt[p * 2048 + wave * 512]);
    }
    __builtin_amdgcn_s_waitcnt(0);
    __syncthreads();
    bf16x8 af[4], bfr[4];
    for (int i = 0; i < 4; ++i)
      af[i] = *(const bf16x8*)&At[(wm + i * 16 + lr) * 32 + lq * 8];
    for (int j = 0; j < 4; ++j)
      bfr[j] = *(const bf16x8*)&Bt[(wn + j * 16 + lr) * 32 + lq * 8];
    for (int i = 0; i < 4; ++i)
      for (int j = 0; j < 4; ++j)
        acc[i][j] = __builtin_amdgcn_mfma_f32_16x16x32_bf16(af[i], bfr[j], acc[i][j], 0, 0, 0);
  }
  uint16_t* C = ga.C[sel] + (size_t)bat * ga.sC[sel];
  for (int i = 0; i < 4; ++i)
    for (int j = 0; j < 4; ++j) {
      int row = m0 + wm + i * 16 + lq * 4;
      int col = n0 + wn + j * 16 + lr;
      float bc = brow ? 0.f : bias[col];
      u16x4 o;
      for (int r = 0; r < 4; ++r) {
        float val = (acc[i][j][r] + (brow ? bias[row + r] : bc)) * os;
        o[r] = f2bf(val);
      }
      *(u16x4*)&C[(size_t)col * ldC + row] = o;
    }
}

// ---------------------------------------------------------------------------
// Output projection, m/n-swapped: A=Ob (m=s), B=Wo (n=c), Y[c][s] fp32 via
// float4 stores. 128(m)x64(n) tiles -> grid (8, 32, 2) = 512 blocks.
// ---------------------------------------------------------------------------
__global__ __launch_bounds__(256) void gemm_out(
    const uint16_t* __restrict__ Ob, long long sA,
    const uint16_t* __restrict__ Wo, float* __restrict__ Y, long long sC,
    const float* __restrict__ bias) {
  constexpr int K = 512;
  __shared__ uint16_t At[128 * 32];
  __shared__ uint16_t Bt[64 * 32];
  const int t = threadIdx.x, lane = t & 63, wave = t >> 6;
  const int lr = lane & 15, lq = lane >> 4;
  const int wm = (wave & 1) * 64, wn = (wave >> 1) * 32;
  const int m0 = blockIdx.y * 128, n0 = blockIdx.x * 64;
  const uint16_t* A = Ob + (size_t)blockIdx.z * sA;
  f32x4 acc[4][2] = {};
  for (int k0 = 0; k0 < K; k0 += 32) {
    __syncthreads();
    for (int p = 0; p < 2; ++p) {
      int u = p * 256 + t;
      int r = u >> 2, c = (u & 3) * 8;
      async16(&A[(size_t)(m0 + r) * K + k0 + c], &At[p * 2048 + wave * 512]);
    }
    {
      int r = t >> 2, c = (t & 3) * 8;
      async16(&Wo[(size_t)(n0 + r) * K + k0 + c], &Bt[wave * 512]);
    }
    __builtin_amdgcn_s_waitcnt(0);
    __syncthreads();
    bf16x8 af[4], bfr[2];
    for (int i = 0; i < 4; ++i)
      af[i] = *(const bf16x8*)&At[(wm + i * 16 + lr) * 32 + lq * 8];
    for (int j = 0; j < 2; ++j)
      bfr[j] = *(const bf16x8*)&Bt[(wn + j * 16 + lr) * 32 + lq * 8];
    for (int i = 0; i < 4; ++i)
      for (int j = 0; j < 2; ++j)
        acc[i][j] = __builtin_amdgcn_mfma_f32_16x16x32_bf16(af[i], bfr[j], acc[i][j], 0, 0, 0);
  }
  float* Cf = Y + (size_t)blockIdx.z * sC;
  for (int i = 0; i < 4; ++i)
    for (int j = 0; j < 2; ++j) {
      int row = m0 + wm + i * 16 + lq * 4;  // s (contiguous)
      int col = n0 + wn + j * 16 + lr;      // c
      float bb = bias[col];
      float4 o = {acc[i][j][0] + bb, acc[i][j][1] + bb,
                  acc[i][j][2] + bb, acc[i][j][3] + bb};
      *(float4*)&Cf[(size_t)col * 4096 + row] = o;
    }
}

// ---------------------------------------------------------------------------
// Flash attention half-range pass, 32x32x16 MFMA. K/V QUAD-buffered,
// barrier every 2 tiles. Q pre-scaled. 512 threads = 8 waves, q-tile 256
// (32 q-rows/wave). grid (S/256, 8, 4): z = jh*2 + b.
// Per wave-tile (64 keys x 32 q-rows):
//   QKT: for jt in 0..1: S32[jt] = sum_ks mfma32(K-frag, Q-frag) (8 mfma).
//   exp/pack: 32 exp + 16 cvt_pk -> W[jt][u] (consecutive-j word pairs).
//   redistribute: per j-slice js: swap32(W[4s+0],W[4s+2]),
//     swap32(W[4s+1],W[4s+3]) -> pa[js] B-frag directly (8 swaps).
//   l-sum: 4 ones-mfma32 into lacc32 (matrix pipe).
//   PV: for dt in 0..1: accOT32[dt] += sum_js mfma32(V-frag, pa[js]) (8).
// 32x32 layouts: C/D col=lane&31, row=(r&3)+8(r>>2)+4*(lane>>5);
// A/B row=lane&31, k=(lane>>5)*8+e.
// K/V LDS tiles XOR-chunk-swizzled (chunk c of row r at c^(r&7)); frag
// reads use chunk (2*slice+hh)^(lane&7) -> even 8-lane/chunk distribution
// = wave-b128 minimum cycles, 0 excess conflicts.
// Writes UNNORMALIZED partial O^T (bf16) + partial l (fp32).
// LDS: Kl 32K + Vl 32K = 64 KB -> 2 blocks/CU (= the register cap anyway).
// ---------------------------------------------------------------------------
__global__ __launch_bounds__(512, 4) void attn128(
    const uint16_t* __restrict__ Q, const uint16_t* __restrict__ K,
    const uint16_t* __restrict__ Vt, uint16_t* __restrict__ Ap,
    float* __restrict__ Lp) {
  constexpr int S = 4096, E = 512;
  const int b = blockIdx.z & 1, jh = blockIdx.z >> 1;
  const int h = blockIdx.y;
  const int i0 = blockIdx.x * 256;
  const int t = threadIdx.x, lane = t & 63, wave = t >> 6;
  const int i31 = lane & 31, hh = lane >> 5, l7 = lane & 7;
  const size_t qkB = (size_t)b * S * E;
  const size_t vB = (size_t)b * E * S;
  __shared__ uint16_t Kl[4][64 * 64];     // [buf][j][d], chunk-swizzled rows
  __shared__ uint16_t Vl[4][64 * 64];     // [buf][d][j], chunk-swizzled rows

  const int qbase = i0 + wave * 32;
  // Q fragments (B-operand, 32x32x16): row = i = lane&31, k = hh*8 + e,
  // k-slice ks covers d in [ks*16, ks*16+16).
  bf16x8 qf[4];
  for (int ks = 0; ks < 4; ++ks)
    qf[ks] = *(const bf16x8*)&Q[qkB + (size_t)(qbase + i31) * E + h * 64 + ks * 16 + hh * 8];

  union { u16x8 u; bf16x8 v; } onesu;
  for (int i = 0; i < 8; ++i) onesu.u[i] = 0x3F80;  // bf16 1.0
  const bf16x8 ones = onesu.v;
  f32x16 lacc32 = {0.f, 0.f, 0.f, 0.f, 0.f, 0.f, 0.f, 0.f,
                   0.f, 0.f, 0.f, 0.f, 0.f, 0.f, 0.f, 0.f};
  f32x16 accOT32[2];
  accOT32[0] = lacc32;
  accOT32[1] = lacc32;
  const f32x16 fz16 = lacc32;  // shared zero C-input for QK^T
  const int srr = t >> 3, ssc = ((t & 7) ^ (srr & 7)) * 8;  // staging row/col

  const int jbeg = jh * (S / 2), jend = jbeg + S / 2;

  // stage one 64-key K/V tile pair into LDS buffer `buf`
  auto stage = [&](int j0, int buf) {
    async16(&K[qkB + (size_t)(j0 + srr) * E + h * 64 + ssc], &Kl[buf][wave * 512]);
    async16(&Vt[vB + (size_t)(h * 64 + srr) * S + j0 + ssc], &Vl[buf][wave * 512]);
  };

  // full compute for one 64-key tile resident in (Kc, Vc)
  auto do_tile = [&](const uint16_t* Kc, const uint16_t* Vc) {
    // ---- QKT per 32-j tile + exp/pack ----
    // S32[jt]: lane holds S^T[j][i=i31], j = jt*32 + (r&3)+8(r>>2)+4hh.
    // cvt_pk(p[2u],p[2u+1]) -> W[jt][u] = [j,j+1] pairs:
    // u=0..7 -> j-offsets {0,1},{2,3},{8,9},{10,11},{16,17},{18,19},
    // {24,25},{26,27} (+4hh, +32jt).
    uint32_t W[2][8];
#pragma unroll
    for (int jt = 0; jt < 2; ++jt) {
      f32x16 s = fz16;
      __builtin_amdgcn_s_setprio(1);
#pragma unroll
      for (int ks = 0; ks < 4; ++ks) {
        bf16x8 ka = *(const bf16x8*)&Kc[(jt * 32 + i31) * 64 + ((2 * ks + hh) ^ l7) * 8];
        s = __builtin_amdgcn_mfma_f32_32x32x16_bf16(ka, qf[ks], s, 0, 0, 0);
      }
      __builtin_amdgcn_s_setprio(0);
#pragma unroll
      for (int u = 0; u < 8; ++u) {
        float p0 = __builtin_amdgcn_exp2f(s[2 * u]);
        float p1 = __builtin_amdgcn_exp2f(s[2 * u + 1]);
        asm("v_cvt_pk_bf16_f32 %0, %1, %2" : "=v"(W[jt][u]) : "v"(p0), "v"(p1));
      }
    }
    // ---- redistribute -> PV B-frags pa[js] (j-slice [js*16, js*16+16)) ----
    // Frag needs P[i][js*16 + hh*8 + 0..7] as 4 words. With jt=js>>1,
    // s16=js&1, base u=4*s16: swap32 semantics a'=[a.lo32|c.lo32],
    // c'=[a.hi32|c.hi32] give:
    //   swap32(W[u0], W[u0+2]) -> F0 (words [+0,1]/[+8,9]) and F2
    //   swap32(W[u0+1], W[u0+3]) -> F1 and F3
    bf16x8 pa[4];
#pragma unroll
    for (int js = 0; js < 4; ++js) {
      const int jt = js >> 1, u0 = (js & 1) * 4;
      uint32_t a0 = W[jt][u0 + 0], a2 = W[jt][u0 + 2];
      uint32_t a1 = W[jt][u0 + 1], a3 = W[jt][u0 + 3];
      asm("v_permlane32_swap_b32 %0, %1" : "+v"(a0), "+v"(a2));
      asm("v_permlane32_swap_b32 %0, %1" : "+v"(a1), "+v"(a3));
      union { uint32_t w[4]; bf16x8 v; } f;
      f.w[0] = a0;  // F0: k-pair 0,1
      f.w[1] = a1;  // F1: k-pair 2,3
      f.w[2] = a2;  // F2: k-pair 4,5
      f.w[3] = a3;  // F3: k-pair 6,7
      pa[js] = f.v;
    }
    // ---- l-sum on the matrix pipe: C[m][i] = sum_j 1*P[i][j] ----
#pragma unroll
    for (int js = 0; js < 4; ++js)
      lacc32 = __builtin_amdgcn_mfma_f32_32x32x16_bf16(ones, pa[js], lacc32, 0, 0, 0);
    // ---- PV in O^T form: A = Vt rows d, B = P rows i, k = j ----
    __builtin_amdgcn_s_setprio(1);
#pragma unroll
    for (int dt = 0; dt < 2; ++dt) {
#pragma unroll
      for (int js = 0; js < 4; ++js) {
        bf16x8 va = *(const bf16x8*)&Vc[(dt * 32 + i31) * 64 + ((2 * js + hh) ^ l7) * 8];
        accOT32[dt] = __builtin_amdgcn_mfma_f32_32x32x16_bf16(va, pa[js], accOT32[dt], 0, 0, 0);
      }
    }
    __builtin_amdgcn_s_setprio(0);
  };

  // prolog: stage first two tiles into buffers 0,1
  stage(jbeg, 0);
  stage(jbeg + 64, 1);
  __builtin_amdgcn_s_waitcnt(0);
  __syncthreads();

  int nb = 0;
  for (int jp = jbeg; jp < jend; jp += 128) {
    // stage the next tile pair into the alternate buffer pair — the DMA
    // flies across BOTH tile computes below.
    if (jp + 128 < jend) {
      stage(jp + 128, nb ^ 2);
      stage(jp + 192, (nb ^ 2) + 1);
    }
    do_tile(Kl[nb], Vl[nb]);
    do_tile(Kl[nb + 1], Vl[nb + 1]);
    // one drain + barrier per 2 tiles
    __builtin_amdgcn_s_waitcnt(0);
    __syncthreads();
    nb ^= 2;
  }
  // epilogue: store partial l and unnormalized partial O.
  // lacc32: all C rows identical (ones-A); lane i (hh=0), reg 0 = l[i].
  // accOT32[dt][r] = O^T[d][i], d = dt*32 + (r&3)+8(r>>2)+4hh: reg quads
  // r=4u..4u+3 are consecutive d -> u16x4 store at d0 = dt*32 + 8u + 4hh.
  uint16_t* Aph = Ap + (size_t)jh * 2 * S * E;
  float* Lph = Lp + ((size_t)(jh * 2 + b) * 8 + h) * S;
  if (lane < 32) Lph[qbase + lane] = lacc32[0];
  const size_t row = qbase + i31;
  for (int dt = 0; dt < 2; ++dt)
    for (int u = 0; u < 4; ++u) {
      u16x4 o;
      for (int r = 0; r < 4; ++r) o[r] = f2bf(accOT32[dt][4 * u + r]);
      *(u16x4*)&Aph[qkB + row * E + h * 64 + dt * 32 + u * 8 + hh * 4] = o;
    }
}

// ---------------------------------------------------------------------------
// Combine: Ob[b][s][e] = (A0+A1) / (l0+l1). 4 elems/thread.
// ---------------------------------------------------------------------------
__global__ __launch_bounds__(256) void attn_combine(
    const uint16_t* __restrict__ Ap, const float* __restrict__ Lp,
    uint16_t* __restrict__ Ob) {
  constexpr int S = 4096, E = 512;
  const size_t HALF = (size_t)2 * S * E;
  const size_t idx = ((size_t)blockIdx.x * 256 + threadIdx.x) * 4;
  const int b = (int)(idx / ((size_t)S * E));
  const size_t rem = idx % ((size_t)S * E);
  const int s = (int)(rem / E), e = (int)(rem % E);
  const int h = e >> 6;
  const float l0 = Lp[((size_t)(0 * 2 + b) * 8 + h) * S + s];
  const float l1 = Lp[((size_t)(1 * 2 + b) * 8 + h) * S + s];
  const float inv = 1.f / (l0 + l1);
  u16x4 a0 = *(const u16x4*)&Ap[idx];
  u16x4 a1 = *(const u16x4*)&Ap[HALF + idx];
  u16x4 o;
  for (int r = 0; r < 4; ++r) o[r] = f2bf((bf2f(a0[r]) + bf2f(a1[r])) * inv);
  *(u16x4*)&Ob[idx] = o;
}

// ---------------------------------------------------------------------------
extern "C" void kernel_launch(void* const* d_in, const int* in_sizes, int n_in,
                              void* d_out, int out_size, void* d_ws, size_t ws_size,
                              hipStream_t stream) {
  const float* x   = (const float*)d_in[0];
  const float* ctx = (const float*)d_in[1];
  const float* Wq  = (const float*)d_in[2];
  const float* bq  = (const float*)d_in[3];
  const float* Wk  = (const float*)d_in[4];
  const float* bk  = (const float*)d_in[5];
  const float* Wv  = (const float*)d_in[6];
  const float* bv  = (const float*)d_in[7];
  const float* Wo  = (const float*)d_in[8];
  const float* bo  = (const float*)d_in[9];
  float* out = (float*)d_out;

  const size_t SZ = (size_t)2 * 4096 * 512;
  uint16_t* xT = (uint16_t*)d_ws;
  uint16_t* cT = xT + SZ;
  uint16_t* Qb = cT + SZ;
  uint16_t* Kb = Qb + SZ;
  uint16_t* Vb = Kb + SZ;    // Vt layout [B][E][S]
  uint16_t* Ob = Vb + SZ;    // attention out [B][S][E]
  uint16_t* Wqb = Ob + SZ;
  uint16_t* Wkb = Wqb + 512 * 512;
  uint16_t* Wvb = Wkb + 512 * 512;
  uint16_t* Wob = Wvb + 512 * 512;
  uint16_t* Ap  = Wob + 512 * 512;            // partial O, [2][B][S][E] bf16
  float*    Lp  = (float*)(Ap + 2 * SZ);      // partial l, [2][B][8][S] fp32
  const long long sIn = 4096LL * 512LL;
  const float slh = 0.125f * 1.44269504088896f;  // SCALE * log2(e)

  cvt_w<<<dim3(256, 4), 256, 0, stream>>>(Wq, Wk, Wv, Wo, Wqb, Wkb, Wvb, Wob);
  transpose_cs<<<dim3(64, 8, 4), 256, 0, stream>>>(x, ctx, xT, cT);
  // fused Q,K,V projections (m/n swapped for vector stores); Q pre-scaled
  QkvArgs qkv = {
      {Wqb, Wkb, cT}, {0, 0, sIn},          // A
      {xT, cT, Wvb}, {sIn, sIn, 0},         // B
      {Qb, Kb, Vb}, {sIn, sIn, sIn},        // C
      {bq, bk, bv},
      {slh, 1.f, 1.f},
      {512, 512, 4096},                      // ldC
      {5, 5, 2},                             // lx = log2(n-tiles)
      {1, 1, 0}};                            // brow
  gemm_qkv<<<dim3(128, 1, 6), 256, 0, stream>>>(qkv);
  attn128<<<dim3(16, 8, 4), 512, 0, stream>>>(Qb, Kb, Vb, Ap, Lp);
  attn_combine<<<dim3(4096), 256, 0, stream>>>(Ap, Lp, Ob);
  // Y[c][s] = sum_e O[s][e] Wo[c][e] + bo[c]  (A=Ob m=s, B=Wo n=c)
  gemm_out<<<dim3(8, 32, 2), 256, 0, stream>>>(Ob, sIn, Wob, out, sIn, bo);
}

// Round 11
// 214.989 us; speedup vs baseline: 1.0709x; 1.0709x over previous
//
#include <hip/hip_runtime.h>
#include <cstdint>

// ---------------------------------------------------------------------------
// AttentionBlock: B=2, C=512, H=W=64 (S=4096), 8 heads x 64 dim.
// I/O dtype: fp32. Internal: bf16 MFMA (16x16x32), fp32 accum.
// R26 = EXACT revert to R24 (best verified: 217.3us total, attn 82.7us).
// R25 post-mortem (32x32x16 shape): NULL on attn (83.3), regressed total;
// SQ_LDS_BANK_CONFLICT 0 -> 8.4M (the 32-row-span XOR-chunk read pattern
// conflicts where the 16-row form measures zero — derivation-level conflict
// models are insufficient, measurement rules); VALU dropped 45.7->39.8 as
// predicted but matrix-pipe busy GREW (32x32 mfma ~8.07 vs 4.85 cyc, lacc
// share doubled) — the pipes stayed ~86% combined issue-busy with load
// merely shifted. Reverted.
// Final-state accounting: attn at 86% dual-pipe issue busy, 0 conflicts;
// 10 rounds of levers: scheduling x7 null (barrier freq, setprio, cohorts,
// source interleave — LLVM already schedules the DAG freely), occupancy-via-
// grid dead (true regs ~128/wave caps 2 blocks/CU), combine-fusion regressed
// (lost async16), 32x32 null. The two wins were work-removal:
//   R16: in-register softmax (exp2 raw + cvt_pk + permlane swaps) -33us
//   R24: l-sum on matrix pipe via ones-MFMA -4us
// B^T-form MFMA: C[m][n] += A[m][k]*B[n][k]; C/D col(n)=lane&15, row(m)=lq*4+reg;
// A/B frag: row=lane&15, k=lq*8+j  (lq = lane>>4).
// ---------------------------------------------------------------------------

typedef __bf16 bf16x8 __attribute__((ext_vector_type(8)));
typedef __bf16 bf16x4 __attribute__((ext_vector_type(4)));
typedef float f32x4 __attribute__((ext_vector_type(4)));
typedef unsigned short u16x8 __attribute__((ext_vector_type(8)));
typedef unsigned short u16x4 __attribute__((ext_vector_type(4)));

#define AS1 __attribute__((address_space(1)))
#define AS3 __attribute__((address_space(3)))

__device__ __forceinline__ void async16(const void* g, void* l) {
  __builtin_amdgcn_global_load_lds((const AS1 void*)g, (AS3 void*)l, 16, 0, 0);
}

__device__ __forceinline__ uint16_t f2bf(float f) {
  union { float f; uint32_t u; } a;
  a.f = f;
  uint32_t r = a.u + 0x7fffu + ((a.u >> 16) & 1u);  // RNE
  return (uint16_t)(r >> 16);
}

__device__ __forceinline__ float bf2f(uint16_t u) {
  union { uint32_t u; float f; } a;
  a.u = (uint32_t)u << 16;
  return a.f;
}

// ---------------------------------------------------------------------------
__global__ __launch_bounds__(256) void cvt_w(
    const float* __restrict__ W0, const float* __restrict__ W1,
    const float* __restrict__ W2, const float* __restrict__ W3,
    uint16_t* __restrict__ O0, uint16_t* __restrict__ O1,
    uint16_t* __restrict__ O2, uint16_t* __restrict__ O3) {
  const float* W[4] = {W0, W1, W2, W3};
  uint16_t* O[4] = {O0, O1, O2, O3};
  const int w = blockIdx.y;
  const int i = (blockIdx.x * 256 + threadIdx.x) * 4;
  float4 v = *(const float4*)&W[w][i];
  u16x4 o = {f2bf(v.x), f2bf(v.y), f2bf(v.z), f2bf(v.w)};
  *(u16x4*)&O[w][i] = o;
}

// ---------------------------------------------------------------------------
// Transpose+convert [C=512][S=4096] fp32 -> [S][C] bf16, x and context.
// ---------------------------------------------------------------------------
__global__ __launch_bounds__(256) void transpose_cs(
    const float* __restrict__ x, const float* __restrict__ ctx,
    uint16_t* __restrict__ xT, uint16_t* __restrict__ cT) {
  const int zz = blockIdx.z;
  const float* src = (zz < 2 ? x : ctx) + (size_t)(zz & 1) * 512 * 4096;
  uint16_t* dst = (zz < 2 ? xT : cT) + (size_t)(zz & 1) * 4096 * 512;
  const int s0 = blockIdx.x * 64, c0 = blockIdx.y * 64;
  __shared__ uint16_t tile[64][80];
  const int t = threadIdx.x;
  for (int p = 0; p < 2; ++p) {
    int u = p * 256 + t;
    int r = u >> 3, cg = (u & 7) * 8;
    const float* sp = &src[(size_t)(c0 + r) * 4096 + s0 + cg];
    float4 v0 = *(const float4*)sp;
    float4 v1 = *(const float4*)(sp + 4);
    u16x8 o = {f2bf(v0.x), f2bf(v0.y), f2bf(v0.z), f2bf(v0.w),
               f2bf(v1.x), f2bf(v1.y), f2bf(v1.z), f2bf(v1.w)};
    *(u16x8*)&tile[r][cg] = o;
  }
  __syncthreads();
  for (int p = 0; p < 2; ++p) {
    int u = p * 256 + t;
    int sr = u >> 3, cg = (u & 7) * 8;
    u16x8 v;
    for (int j = 0; j < 8; ++j) v[j] = tile[cg + j][sr];
    *(u16x8*)&dst[(size_t)(s0 + sr) * 512 + c0 + cg] = v;
  }
}

// ---------------------------------------------------------------------------
// Fused QKV projection. blockIdx.z = sel*2 + batch, sel in {0:Q, 1:K, 2:V}.
// C[m][n] = (sum_k A[m][k]*B[n][k] + bias) * os, stored at C[col*ldC + row]
// (row = m is the contiguous dim -> u16x4 stores).
// Q/K: A=W (m=e), B=xT/cT (n=s), out Q[s][e] (ldC=512), bias by row.
// V:   A=cT (m=s), B=Wv (n=e), out Vt[e][s] (ldC=4096), bias by col.
// ---------------------------------------------------------------------------
struct QkvArgs {
  const uint16_t* A[3]; long long sA[3];
  const uint16_t* B[3]; long long sB[3];
  uint16_t* C[3];       long long sC[3];
  const float* bias[3];
  float os[3];
  long long ldC[3]; int lx[3]; int brow[3];
};

__global__ __launch_bounds__(256) void gemm_qkv(QkvArgs ga) {
  constexpr int K = 512;
  __shared__ uint16_t At[128 * 32];
  __shared__ uint16_t Bt[128 * 32];
  const int t = threadIdx.x, lane = t & 63, wave = t >> 6;
  const int lr = lane & 15, lq = lane >> 4;
  const int wm = (wave >> 1) * 64, wn = (wave & 1) * 64;
  const int sel = blockIdx.z >> 1, bat = blockIdx.z & 1;
  const int lx = ga.lx[sel], brow = ga.brow[sel];
  const long long ldC = ga.ldC[sel];
  const float os = ga.os[sel];
  const int n0 = (blockIdx.x & ((1 << lx) - 1)) * 128;
  const int m0 = (blockIdx.x >> lx) * 128;
  const uint16_t* A = ga.A[sel] + (size_t)bat * ga.sA[sel];
  const uint16_t* B = ga.B[sel] + (size_t)bat * ga.sB[sel];
  const float* bias = ga.bias[sel];
  f32x4 acc[4][4] = {};
  for (int k0 = 0; k0 < K; k0 += 32) {
    __syncthreads();
    for (int p = 0; p < 2; ++p) {
      int u = p * 256 + t;
      int r = u >> 2, c = (u & 3) * 8;
      async16(&A[(size_t)(m0 + r) * K + k0 + c], &At[p * 2048 + wave * 512]);
      async16(&B[(size_t)(n0 + r) * K + k0 + c], &Bt[p * 2048 + wave * 512]);
    }
    __builtin_amdgcn_s_waitcnt(0);
    __syncthreads();
    bf16x8 af[4], bfr[4];
    for (int i = 0; i < 4; ++i)
      af[i] = *(const bf16x8*)&At[(wm + i * 16 + lr) * 32 + lq * 8];
    for (int j = 0; j < 4; ++j)
      bfr[j] = *(const bf16x8*)&Bt[(wn + j * 16 + lr) * 32 + lq * 8];
    for (int i = 0; i < 4; ++i)
      for (int j = 0; j < 4; ++j)
        acc[i][j] = __builtin_amdgcn_mfma_f32_16x16x32_bf16(af[i], bfr[j], acc[i][j], 0, 0, 0);
  }
  uint16_t* C = ga.C[sel] + (size_t)bat * ga.sC[sel];
  for (int i = 0; i < 4; ++i)
    for (int j = 0; j < 4; ++j) {
      int row = m0 + wm + i * 16 + lq * 4;
      int col = n0 + wn + j * 16 + lr;
      float bc = brow ? 0.f : bias[col];
      u16x4 o;
      for (int r = 0; r < 4; ++r) {
        float val = (acc[i][j][r] + (brow ? bias[row + r] : bc)) * os;
        o[r] = f2bf(val);
      }
      *(u16x4*)&C[(size_t)col * ldC + row] = o;
    }
}

// ---------------------------------------------------------------------------
// Output projection, m/n-swapped: A=Ob (m=s), B=Wo (n=c), Y[c][s] fp32 via
// float4 stores. 128(m)x64(n) tiles -> grid (8, 32, 2) = 512 blocks.
// ---------------------------------------------------------------------------
__global__ __launch_bounds__(256) void gemm_out(
    const uint16_t* __restrict__ Ob, long long sA,
    const uint16_t* __restrict__ Wo, float* __restrict__ Y, long long sC,
    const float* __restrict__ bias) {
  constexpr int K = 512;
  __shared__ uint16_t At[128 * 32];
  __shared__ uint16_t Bt[64 * 32];
  const int t = threadIdx.x, lane = t & 63, wave = t >> 6;
  const int lr = lane & 15, lq = lane >> 4;
  const int wm = (wave & 1) * 64, wn = (wave >> 1) * 32;
  const int m0 = blockIdx.y * 128, n0 = blockIdx.x * 64;
  const uint16_t* A = Ob + (size_t)blockIdx.z * sA;
  f32x4 acc[4][2] = {};
  for (int k0 = 0; k0 < K; k0 += 32) {
    __syncthreads();
    for (int p = 0; p < 2; ++p) {
      int u = p * 256 + t;
      int r = u >> 2, c = (u & 3) * 8;
      async16(&A[(size_t)(m0 + r) * K + k0 + c], &At[p * 2048 + wave * 512]);
    }
    {
      int r = t >> 2, c = (t & 3) * 8;
      async16(&Wo[(size_t)(n0 + r) * K + k0 + c], &Bt[wave * 512]);
    }
    __builtin_amdgcn_s_waitcnt(0);
    __syncthreads();
    bf16x8 af[4], bfr[2];
    for (int i = 0; i < 4; ++i)
      af[i] = *(const bf16x8*)&At[(wm + i * 16 + lr) * 32 + lq * 8];
    for (int j = 0; j < 2; ++j)
      bfr[j] = *(const bf16x8*)&Bt[(wn + j * 16 + lr) * 32 + lq * 8];
    for (int i = 0; i < 4; ++i)
      for (int j = 0; j < 2; ++j)
        acc[i][j] = __builtin_amdgcn_mfma_f32_16x16x32_bf16(af[i], bfr[j], acc[i][j], 0, 0, 0);
  }
  float* Cf = Y + (size_t)blockIdx.z * sC;
  for (int i = 0; i < 4; ++i)
    for (int j = 0; j < 2; ++j) {
      int row = m0 + wm + i * 16 + lq * 4;  // s (contiguous)
      int col = n0 + wn + j * 16 + lr;      // c
      float bb = bias[col];
      float4 o = {acc[i][j][0] + bb, acc[i][j][1] + bb,
                  acc[i][j][2] + bb, acc[i][j][3] + bb};
      *(float4*)&Cf[(size_t)col * 4096 + row] = o;
    }
}

// ---------------------------------------------------------------------------
// Flash attention half-range pass, K/V QUAD-buffered, barrier every 2 tiles.
// Q pre-scaled. 512 threads = 8 waves, q-tile 256. grid (S/256, 8, 4):
// z = jh*2 + b. Per 2-tile period: stage next pair of tiles (DMA flies
// across both computes), compute tile A, compute tile B, waitcnt(0)+barrier.
// do_tile: Phase A = QKT jn0,1 (pure MFMA); Phase B = QKT jn2,3 interleaved
// with exp/pack of jn0,1; then exp/pack jn2,3, permlane, l-sum via
// ones-vector MFMA on packed pa (matrix pipe), PV.
// Softmax fully in-register: raw v_exp_f32, v_cvt_pk_bf16_f32 packing, and
// permlane{32,16}_swap redistribution of P into PV B-fragments (no P LDS).
// Writes UNNORMALIZED partial O^T (bf16) + partial l (fp32).
// K/V LDS tiles XOR-chunk-swizzled: 16B chunk c of row r stored at c^(r&7).
// LDS: Kl 32K + Vl 32K = 64 KB -> 2 blocks/CU (= the register cap anyway).
// ---------------------------------------------------------------------------
__global__ __launch_bounds__(512, 4) void attn128(
    const uint16_t* __restrict__ Q, const uint16_t* __restrict__ K,
    const uint16_t* __restrict__ Vt, uint16_t* __restrict__ Ap,
    float* __restrict__ Lp) {
  constexpr int S = 4096, E = 512;
  const int b = blockIdx.z & 1, jh = blockIdx.z >> 1;
  const int h = blockIdx.y;
  const int i0 = blockIdx.x * 256;
  const int t = threadIdx.x, lane = t & 63, wave = t >> 6;
  const int lr = lane & 15, lq = lane >> 4;
  const size_t qkB = (size_t)b * S * E;
  const size_t vB = (size_t)b * E * S;
  __shared__ uint16_t Kl[4][64 * 64];     // [buf][j][d], chunk-swizzled rows
  __shared__ uint16_t Vl[4][64 * 64];     // [buf][d][j], chunk-swizzled rows

  const int qbase = i0 + wave * 32;
  bf16x8 qf[2][2];
  for (int g = 0; g < 2; ++g) {
    const size_t qo = qkB + (size_t)(qbase + g * 16 + lr) * E + h * 64 + lq * 8;
    qf[g][0] = *(const bf16x8*)&Q[qo];
    qf[g][1] = *(const bf16x8*)&Q[qo + 32];
  }
  union { u16x8 u; bf16x8 v; } onesu;
  for (int i = 0; i < 8; ++i) onesu.u[i] = 0x3F80;  // bf16 1.0
  const bf16x8 ones = onesu.v;
  f32x4 lacc[2] = {};
  f32x4 accOT[2][4] = {};
  const f32x4 fz = {0.f, 0.f, 0.f, 0.f};  // shared zero C-input for QK^T
  const int swz = (lr & 7);
  const int srr = t >> 3, ssc = ((t & 7) ^ (srr & 7)) * 8;  // staging row/col

  const int jbeg = jh * (S / 2), jend = jbeg + S / 2;

  // stage one 64-key K/V tile pair into LDS buffer `buf`
  auto stage = [&](int j0, int buf) {
    async16(&K[qkB + (size_t)(j0 + srr) * E + h * 64 + ssc], &Kl[buf][wave * 512]);
    async16(&Vt[vB + (size_t)(h * 64 + srr) * S + j0 + ssc], &Vl[buf][wave * 512]);
  };

  // full compute for one 64-key tile resident in (Kc, Vc)
  auto do_tile = [&](const uint16_t* Kc, const uint16_t* Vc) {
    const int c0 = (lq ^ swz) * 8;
    f32x4 sv[2][4];
    uint32_t pk[2][4][2];
    // ---- Phase A: QKT jn=0,1 (pure MFMA) ----
    __builtin_amdgcn_s_setprio(1);
#pragma unroll
    for (int jn = 0; jn < 2; ++jn) {
      const int row = jn * 16 + lr;
      bf16x8 ka0 = *(const bf16x8*)&Kc[row * 64 + c0];
      bf16x8 ka1 = *(const bf16x8*)&Kc[row * 64 + (c0 ^ 32)];
#pragma unroll
      for (int g = 0; g < 2; ++g) {
        f32x4 z = __builtin_amdgcn_mfma_f32_16x16x32_bf16(ka0, qf[g][0], fz, 0, 0, 0);
        z = __builtin_amdgcn_mfma_f32_16x16x32_bf16(ka1, qf[g][1], z, 0, 0, 0);
        sv[g][jn] = z;
      }
    }
    __builtin_amdgcn_s_setprio(0);
    // ---- Phase B: QKT jn=2,3 (MFMA) || exp/pack jn=0,1 (VALU) ----
#pragma unroll
    for (int jn = 2; jn < 4; ++jn) {
      const int row = jn * 16 + lr;
      bf16x8 ka0 = *(const bf16x8*)&Kc[row * 64 + c0];
      bf16x8 ka1 = *(const bf16x8*)&Kc[row * 64 + (c0 ^ 32)];
#pragma unroll
      for (int g = 0; g < 2; ++g) {
        f32x4 z = __builtin_amdgcn_mfma_f32_16x16x32_bf16(ka0, qf[g][0], fz, 0, 0, 0);
        z = __builtin_amdgcn_mfma_f32_16x16x32_bf16(ka1, qf[g][1], z, 0, 0, 0);
        sv[g][jn] = z;
        // interleave: exp/pack of the jn-2 quad (independent of this QKT)
        f32x4 p;
#pragma unroll
        for (int r = 0; r < 4; ++r) p[r] = __builtin_amdgcn_exp2f(sv[g][jn - 2][r]);
        asm("v_cvt_pk_bf16_f32 %0, %1, %2" : "=v"(pk[g][jn - 2][0]) : "v"(p[0]), "v"(p[1]));
        asm("v_cvt_pk_bf16_f32 %0, %1, %2" : "=v"(pk[g][jn - 2][1]) : "v"(p[2]), "v"(p[3]));
      }
    }
    // ---- exp/pack jn=2,3 ----
#pragma unroll
    for (int g = 0; g < 2; ++g) {
#pragma unroll
      for (int jn = 2; jn < 4; ++jn) {
        f32x4 p;
#pragma unroll
        for (int r = 0; r < 4; ++r) p[r] = __builtin_amdgcn_exp2f(sv[g][jn][r]);
        asm("v_cvt_pk_bf16_f32 %0, %1, %2" : "=v"(pk[g][jn][0]) : "v"(p[0]), "v"(p[1]));
        asm("v_cvt_pk_bf16_f32 %0, %1, %2" : "=v"(pk[g][jn][1]) : "v"(p[2]), "v"(p[3]));
      }
    }
    // ---- permlane both halves -> pa[g][half]; l-sum on matrix pipe ----
    // Source lane (lr,lq) holds P[lr][jn*16+lq*4+r]; target needs
    // P[lr][lq*8+jj] (pa[0]) / P[lr][32+lq*8+jj] (pa[1]).
    bf16x8 pa[2][2];
#pragma unroll
    for (int g = 0; g < 2; ++g) {
#pragma unroll
      for (int half = 0; half < 2; ++half) {
        union { uint32_t w[4]; bf16x8 v; } f;
#pragma unroll
        for (int p_ = 0; p_ < 2; ++p_) {
          uint32_t a = pk[g][2 * half][p_];       // jn = 2*half
          uint32_t c = pk[g][2 * half + 1][p_];   // jn = 2*half+1
          // swap32: a=[a r0,a r1,c r0,c r1], c=[a r2,a r3,c r2,c r3]
          asm("v_permlane32_swap_b32 %0, %1" : "+v"(a), "+v"(c));
          // swap16: a=[a r0,c r0,a r2,c r2] = frag word u=p_;
          //         c=[a r1,c r1,a r3,c r3] = frag word u=2+p_
          asm("v_permlane16_swap_b32 %0, %1" : "+v"(a), "+v"(c));
          f.w[p_] = a;
          f.w[2 + p_] = c;
        }
        pa[g][half] = f.v;
      }
      // l-sum on the MFMA pipe (R17-verified): C[m][n] = sum_j 1*P[i=n][j];
      // every m-row identical, col n = lr -> lane lr holds row-i sum.
      lacc[g] = __builtin_amdgcn_mfma_f32_16x16x32_bf16(ones, pa[g][0], lacc[g], 0, 0, 0);
      lacc[g] = __builtin_amdgcn_mfma_f32_16x16x32_bf16(ones, pa[g][1], lacc[g], 0, 0, 0);
    }
    // ---- PV in O^T form: A = Vt rows d (k=j), B = P rows i (k=j) ----
    __builtin_amdgcn_s_setprio(1);
#pragma unroll
    for (int dn = 0; dn < 4; ++dn) {
      const int row = dn * 16 + lr;
      bf16x8 v0 = *(const bf16x8*)&Vc[row * 64 + c0];
      bf16x8 v1 = *(const bf16x8*)&Vc[row * 64 + (c0 ^ 32)];
#pragma unroll
      for (int g = 0; g < 2; ++g) {
        accOT[g][dn] = __builtin_amdgcn_mfma_f32_16x16x32_bf16(v0, pa[g][0], accOT[g][dn], 0, 0, 0);
        accOT[g][dn] = __builtin_amdgcn_mfma_f32_16x16x32_bf16(v1, pa[g][1], accOT[g][dn], 0, 0, 0);
      }
    }
    __builtin_amdgcn_s_setprio(0);
  };

  // prolog: stage first two tiles into buffers 0,1
  stage(jbeg, 0);
  stage(jbeg + 64, 1);
  __builtin_amdgcn_s_waitcnt(0);
  __syncthreads();

  int nb = 0;
  for (int jp = jbeg; jp < jend; jp += 128) {
    // stage the next tile pair into the alternate buffer pair — the DMA
    // flies across BOTH tile computes below.
    if (jp + 128 < jend) {
      stage(jp + 128, nb ^ 2);
      stage(jp + 192, (nb ^ 2) + 1);
    }
    do_tile(Kl[nb], Vl[nb]);
    do_tile(Kl[nb + 1], Vl[nb + 1]);
    // one drain + barrier per 2 tiles
    __builtin_amdgcn_s_waitcnt(0);
    __syncthreads();
    nb ^= 2;
  }
  // epilogue: store partial l (per query row) and unnormalized partial O.
  // lacc: every m-row identical; lane lr (lq=0, reg 0) holds l for q-row lr.
  uint16_t* Aph = Ap + (size_t)jh * 2 * S * E;
  float* Lph = Lp + ((size_t)(jh * 2 + b) * 8 + h) * S;
  for (int g = 0; g < 2; ++g) {
    if (lane < 16) Lph[qbase + g * 16 + lr] = lacc[g][0];
    const size_t row = qbase + g * 16 + lr;
    for (int dn = 0; dn < 4; ++dn) {
      u16x4 o;
      for (int r = 0; r < 4; ++r) o[r] = f2bf(accOT[g][dn][r]);
      *(u16x4*)&Aph[qkB + row * E + h * 64 + dn * 16 + lq * 4] = o;
    }
  }
}

// ---------------------------------------------------------------------------
// Combine: Ob[b][s][e] = (A0+A1) / (l0+l1). 4 elems/thread.
// ---------------------------------------------------------------------------
__global__ __launch_bounds__(256) void attn_combine(
    const uint16_t* __restrict__ Ap, const float* __restrict__ Lp,
    uint16_t* __restrict__ Ob) {
  constexpr int S = 4096, E = 512;
  const size_t HALF = (size_t)2 * S * E;
  const size_t idx = ((size_t)blockIdx.x * 256 + threadIdx.x) * 4;
  const int b = (int)(idx / ((size_t)S * E));
  const size_t rem = idx % ((size_t)S * E);
  const int s = (int)(rem / E), e = (int)(rem % E);
  const int h = e >> 6;
  const float l0 = Lp[((size_t)(0 * 2 + b) * 8 + h) * S + s];
  const float l1 = Lp[((size_t)(1 * 2 + b) * 8 + h) * S + s];
  const float inv = 1.f / (l0 + l1);
  u16x4 a0 = *(const u16x4*)&Ap[idx];
  u16x4 a1 = *(const u16x4*)&Ap[HALF + idx];
  u16x4 o;
  for (int r = 0; r < 4; ++r) o[r] = f2bf((bf2f(a0[r]) + bf2f(a1[r])) * inv);
  *(u16x4*)&Ob[idx] = o;
}

// ---------------------------------------------------------------------------
extern "C" void kernel_launch(void* const* d_in, const int* in_sizes, int n_in,
                              void* d_out, int out_size, void* d_ws, size_t ws_size,
                              hipStream_t stream) {
  const float* x   = (const float*)d_in[0];
  const float* ctx = (const float*)d_in[1];
  const float* Wq  = (const float*)d_in[2];
  const float* bq  = (const float*)d_in[3];
  const float* Wk  = (const float*)d_in[4];
  const float* bk  = (const float*)d_in[5];
  const float* Wv  = (const float*)d_in[6];
  const float* bv  = (const float*)d_in[7];
  const float* Wo  = (const float*)d_in[8];
  const float* bo  = (const float*)d_in[9];
  float* out = (float*)d_out;

  const size_t SZ = (size_t)2 * 4096 * 512;
  uint16_t* xT = (uint16_t*)d_ws;
  uint16_t* cT = xT + SZ;
  uint16_t* Qb = cT + SZ;
  uint16_t* Kb = Qb + SZ;
  uint16_t* Vb = Kb + SZ;    // Vt layout [B][E][S]
  uint16_t* Ob = Vb + SZ;    // attention out [B][S][E]
  uint16_t* Wqb = Ob + SZ;
  uint16_t* Wkb = Wqb + 512 * 512;
  uint16_t* Wvb = Wkb + 512 * 512;
  uint16_t* Wob = Wvb + 512 * 512;
  uint16_t* Ap  = Wob + 512 * 512;            // partial O, [2][B][S][E] bf16
  float*    Lp  = (float*)(Ap + 2 * SZ);      // partial l, [2][B][8][S] fp32
  const long long sIn = 4096LL * 512LL;
  const float slh = 0.125f * 1.44269504088896f;  // SCALE * log2(e)

  cvt_w<<<dim3(256, 4), 256, 0, stream>>>(Wq, Wk, Wv, Wo, Wqb, Wkb, Wvb, Wob);
  transpose_cs<<<dim3(64, 8, 4), 256, 0, stream>>>(x, ctx, xT, cT);
  // fused Q,K,V projections (m/n swapped for vector stores); Q pre-scaled
  QkvArgs qkv = {
      {Wqb, Wkb, cT}, {0, 0, sIn},          // A
      {xT, cT, Wvb}, {sIn, sIn, 0},         // B
      {Qb, Kb, Vb}, {sIn, sIn, sIn},        // C
      {bq, bk, bv},
      {slh, 1.f, 1.f},
      {512, 512, 4096},                      // ldC
      {5, 5, 2},                             // lx = log2(n-tiles)
      {1, 1, 0}};                            // brow
  gemm_qkv<<<dim3(128, 1, 6), 256, 0, stream>>>(qkv);
  attn128<<<dim3(16, 8, 4), 512, 0, stream>>>(Qb, Kb, Vb, Ap, Lp);
  attn_combine<<<dim3(4096), 256, 0, stream>>>(Ap, Lp, Ob);
  // Y[c][s] = sum_e O[s][e] Wo[c][e] + bo[c]  (A=Ob m=s, B=Wo n=c)
  gemm_out<<<dim3(8, 32, 2), 256, 0, stream>>>(Ob, sIn, Wob, out, sIn, bo);
}